// Round 1
// baseline (488.837 us; speedup 1.0000x reference)
//
#include <hip/hip_runtime.h>
#include <math.h>

#define B_ 2
#define S_ 2048
#define D_ 1024
#define H_ 16
#define DK_ 64

typedef __attribute__((ext_vector_type(8))) short bf16x8;
typedef __attribute__((ext_vector_type(4))) float f32x4;

#define MFMA16(a, b, c) __builtin_amdgcn_mfma_f32_16x16x32_bf16((a), (b), (c), 0, 0, 0)

#define ASYNC16(g, l)                                                          \
    __builtin_amdgcn_global_load_lds(                                          \
        (const __attribute__((address_space(1))) void*)(g),                    \
        (__attribute__((address_space(3))) void*)(l), 16, 0, 0)

#define LOG2E 1.4426950408889634f

__device__ __forceinline__ unsigned short f2bf(float x) {
    unsigned int u = __float_as_uint(x);
    unsigned int r = (u + 0x7fffu + ((u >> 16) & 1u)) >> 16;
    return (unsigned short)r;
}

// ---------------------------------------------------------------------------
// pack: fp32 -> bf16 (plain), z selects tensor.
// ---------------------------------------------------------------------------
__global__ __launch_bounds__(256)
void pack_all(const float* __restrict__ q, const float* __restrict__ k,
              const float* __restrict__ v, const float* __restrict__ wq,
              const float* __restrict__ wk, const float* __restrict__ wv,
              const float* __restrict__ wo, unsigned short* __restrict__ ws0)
{
    const int z = blockIdx.z;
    const size_t IN = 4194304, WT = 1048576;
    const float* in;
    unsigned short* dst;
    int n;
    switch (z) {
        case 0: in = q;  dst = ws0;            n = (int)IN; break;
        case 1: in = k;  dst = ws0 + IN;       n = (int)IN; break;
        case 2: in = v;  dst = ws0 + 2*IN;     n = (int)IN; break;
        case 3: in = wq; dst = ws0 + 3*IN;          n = (int)WT; break;
        case 4: in = wk; dst = ws0 + 3*IN + WT;     n = (int)WT; break;
        case 5: in = wv; dst = ws0 + 3*IN + 2*WT;   n = (int)WT; break;
        default:in = wo; dst = ws0 + 3*IN + 3*WT;   n = (int)WT; break;
    }
    const int n4 = n >> 2;
    const int stride = gridDim.x * blockDim.x;
    for (int i = blockIdx.x * blockDim.x + threadIdx.x; i < n4; i += stride) {
        float4 x = ((const float4*)in)[i];
        ushort4 hv;
        hv.x = f2bf(x.x); hv.y = f2bf(x.y); hv.z = f2bf(x.z); hv.w = f2bf(x.w);
        ((ushort4*)dst)[i] = hv;
    }
}

// ---------------------------------------------------------------------------
// bf16 GEMM core, 512 thr / 8 waves: acc += A(M,K).B(N,K)^T.  128x128 tile,
// BK=64, wave tile 64x32 (2x4 wave grid).  128B LDS rows + XOR-8 swizzle.
// ---------------------------------------------------------------------------
__device__ __forceinline__ void gemm_core512(
    const unsigned short* __restrict__ A, const unsigned short* __restrict__ B,
    unsigned short* As, unsigned short* Bs, int m0, int n0, f32x4 (&acc)[4][2])
{
    const int tid  = threadIdx.x;
    const int w    = tid >> 6;
    const int lane = tid & 63;
    const int rA   = lane & 15;
    const int quad = lane >> 4;
    const int wm   = (w & 1) * 64;
    const int wn   = (w >> 1) * 32;

#pragma unroll 1
    for (int k0 = 0; k0 < 1024; k0 += 64) {
        __syncthreads();
#pragma unroll
        for (int i = 0; i < 2; ++i) {
            const int c   = i * 512 + tid;
            const int row = c >> 3;
            const int g   = (c & 7) ^ (row & 7);
            ASYNC16(A + (size_t)(m0 + row) * 1024 + k0 + g * 8,
                    As + (size_t)(i * 512 + w * 64) * 8);
            ASYNC16(B + (size_t)(n0 + row) * 1024 + k0 + g * 8,
                    Bs + (size_t)(i * 512 + w * 64) * 8);
        }
        __syncthreads();
#pragma unroll
        for (int ks = 0; ks < 2; ++ks) {
            bf16x8 a[4], bb2[2];
#pragma unroll
            for (int mt = 0; mt < 4; ++mt) {
                const int row = wm + mt * 16 + rA;
                a[mt] = *(const bf16x8*)&As[row * 64 + (((ks * 4 + quad) ^ (row & 7)) * 8)];
            }
#pragma unroll
            for (int nt = 0; nt < 2; ++nt) {
                const int row = wn + nt * 16 + rA;
                bb2[nt] = *(const bf16x8*)&Bs[row * 64 + (((ks * 4 + quad) ^ (row & 7)) * 8)];
            }
#pragma unroll
            for (int mt = 0; mt < 4; ++mt)
#pragma unroll
                for (int nt = 0; nt < 2; ++nt)
                    acc[mt][nt] = MFMA16(a[mt], bb2[nt], acc[mt][nt]);
        }
    }
}

// QKV projections.  q,k -> (b,h,s,dk); v -> (b,h,dk,s).
// q pre-scaled by 0.125*log2(e) so attention uses exp2 directly.
__global__ __launch_bounds__(512, 4)
void gemm_qkv(const unsigned short* __restrict__ ws0,
              const float* __restrict__ bq, const float* __restrict__ bk,
              const float* __restrict__ bv,
              unsigned short* __restrict__ qbuf, unsigned short* __restrict__ kbuf,
              unsigned short* __restrict__ vtbuf)
{
    __shared__ unsigned short As[128 * 64];
    __shared__ unsigned short Bs[128 * 64];
    const size_t IN = 4194304, WT = 1048576;
    const int z = blockIdx.z;
    const unsigned short* Ap = ws0 + (size_t)z * IN;
    const unsigned short* Bp = ws0 + 3 * IN + (size_t)z * WT;
    const float* bias = (z == 0) ? bq : (z == 1) ? bk : bv;
    unsigned short* dst = (z == 0) ? qbuf : (z == 1) ? kbuf : vtbuf;

    const int m0 = blockIdx.y * 128;
    const int n0 = blockIdx.x * 128;
    f32x4 acc[4][2] = {};
    gemm_core512(Ap, Bp, As, Bs, m0, n0, acc);

    const int tid = threadIdx.x, w = tid >> 6, lane = tid & 63;
    const int quad = lane >> 4, col = lane & 15;
    const int wm = (w & 1) * 64, wn = (w >> 1) * 32;
    const float qscale = (z == 0) ? (0.125f * LOG2E) : 1.0f;
#pragma unroll
    for (int mt = 0; mt < 4; ++mt)
#pragma unroll
        for (int nt = 0; nt < 2; ++nt) {
            f32x4 v = acc[mt][nt];
#pragma unroll
            for (int r = 0; r < 4; ++r) {
                const int m = m0 + wm + mt * 16 + quad * 4 + r;
                const int n = n0 + wn + nt * 16 + col;
                const float val = (v[r] + bias[n]) * qscale;
                const int bb = m >> 11, ss = m & 2047;
                const int hh = n >> 6, dd = n & 63;
                if (z == 2)
                    dst[((size_t)(bb * 16 + hh) * 64 + dd) * 2048 + ss] = f2bf(val);
                else
                    dst[((size_t)(bb * 16 + hh) * 2048 + ss) * 64 + dd] = f2bf(val);
            }
        }
}

// Output projection: out = ctx(bf16) . Wo^T + bo, fp32 out.
__global__ __launch_bounds__(512, 4)
void gemm_out(const unsigned short* __restrict__ Actx,
              const unsigned short* __restrict__ Bwo,
              const float* __restrict__ bias, float* __restrict__ out)
{
    __shared__ unsigned short As[128 * 64];
    __shared__ unsigned short Bs[128 * 64];
    const int m0 = blockIdx.y * 128;
    const int n0 = blockIdx.x * 128;
    f32x4 acc[4][2] = {};
    gemm_core512(Actx, Bwo, As, Bs, m0, n0, acc);

    const int tid = threadIdx.x, w = tid >> 6, lane = tid & 63;
    const int quad = lane >> 4, col = lane & 15;
    const int wm = (w & 1) * 64, wn = (w >> 1) * 32;
#pragma unroll
    for (int mt = 0; mt < 4; ++mt)
#pragma unroll
        for (int nt = 0; nt < 2; ++nt) {
            f32x4 v = acc[mt][nt];
#pragma unroll
            for (int r = 0; r < 4; ++r) {
                const int m = m0 + wm + mt * 16 + quad * 4 + r;
                const int n = n0 + wn + nt * 16 + col;
                out[(size_t)m * 1024 + n] = v[r] + bias[n];
            }
        }
}

// ---------------------------------------------------------------------------
// Flash attention, 1024 threads = 16 waves (8 q-groups x 2 k/d-halves), so
// 2 blocks/CU = 32 waves/CU (100% occupancy; was 16 waves at 512 thr).
// Wave (qg, kh): QK over k-cols [kh*32, kh*32+32), PV over d-cols
// [kh*32, kh*32+32).  Triple-buffered K/V (stage t+2 issued post-B1),
// single Ps (128x64).  Two barriers per tile:
//   B1 = __syncthreads  (drains stage(t+1), publishes Ps(t))
//   B2 = raw s_barrier + lgkmcnt(0) only (Ps read-before-overwrite; the
//        in-flight stage(t+2)/posr(t+1) loads are NOT drained -> they keep
//        a full softmax+PV+QK of latency cover before B1(t+1) drains them).
// lsum is a per-half partial, combined once via LDS at the epilogue.
// ---------------------------------------------------------------------------
__global__ __launch_bounds__(1024, 8)
void attn_mfma(const unsigned short* __restrict__ qbuf,
               const unsigned short* __restrict__ kbuf,
               const unsigned short* __restrict__ vtbuf,
               const float* __restrict__ posr, const int* __restrict__ mask,
               unsigned short* __restrict__ ctxb)
{
    __shared__ unsigned short Ks[3][64 * 64];
    __shared__ unsigned short Vts[3][64 * 64];
    __shared__ unsigned short Ps[128 * 64];

    const int tid  = threadIdx.x;
    const int w    = tid >> 6;          // wave 0..15
    const int lane = tid & 63;
    const int quad = lane >> 4;
    const int col  = lane & 15;
    const int qg   = w >> 1;            // q-group 0..7 (16 rows each)
    const int kh   = w & 1;             // k-half for QK, d-half for PV
    const int q0   = blockIdx.x * 128;
    const int h    = blockIdx.y;
    const int b    = blockIdx.z;

    const size_t headoff = (size_t)(b * 16 + h) * 2048 * 64;
    const unsigned short* Qh  = qbuf + headoff + (size_t)q0 * 64;
    const unsigned short* Kh  = kbuf + headoff;
    const unsigned short* Vth = vtbuf + headoff;

    // staging: waves 0..7 stage K (1 chunk/lane), waves 8..15 stage V
    const int sid  = tid & 511;
    const int srow = sid >> 3;
    const int sg   = (sid & 7) ^ (srow & 7);
    const bool isK = (tid < 512);

    // Q fragments (A-layout: m=col, k=ks*32+quad*8+j) straight from global
    bf16x8 qf[2];
#pragma unroll
    for (int ks = 0; ks < 2; ++ks)
        qf[ks] = *(const bf16x8*)&Qh[(size_t)(qg * 16 + col) * 64 + ks * 32 + quad * 8];

    const float* prq[4];
#pragma unroll
    for (int r = 0; r < 4; ++r)
        prq[r] = posr + ((size_t)b * 2048 + (q0 + qg * 16 + quad * 4 + r)) * 2048 + kh * 32;
    const int* mrow = mask + (size_t)b * 2048 + kh * 32;

    // posr/mask for tile 0
    float pr[4][2];
    int   mk[2];
#pragma unroll
    for (int r = 0; r < 4; ++r)
#pragma unroll
        for (int nt = 0; nt < 2; ++nt) pr[r][nt] = prq[r][nt * 16 + col];
#pragma unroll
    for (int nt = 0; nt < 2; ++nt) mk[nt] = mrow[nt * 16 + col];

    // stage tiles 0,1
    if (isK) {
        ASYNC16(Kh + (size_t)srow * 64 + sg * 8,         &Ks[0][(size_t)(w * 64) * 8]);
        ASYNC16(Kh + (size_t)(64 + srow) * 64 + sg * 8,  &Ks[1][(size_t)(w * 64) * 8]);
    } else {
        ASYNC16(Vth + (size_t)srow * 2048 + sg * 8,      &Vts[0][(size_t)((w - 8) * 64) * 8]);
        ASYNC16(Vth + (size_t)srow * 2048 + 64 + sg * 8, &Vts[1][(size_t)((w - 8) * 64) * 8]);
    }

    f32x4 O[2] = {};
    f32x4 sc[2];
    float lsum[4] = {0.f, 0.f, 0.f, 0.f};

    __syncthreads();                    // tiles 0,1 staged

    // QK(0)
#pragma unroll
    for (int nt = 0; nt < 2; ++nt) sc[nt] = (f32x4){0.f, 0.f, 0.f, 0.f};
#pragma unroll
    for (int ks = 0; ks < 2; ++ks)
#pragma unroll
        for (int nt = 0; nt < 2; ++nt) {
            const bf16x8 bk = *(const bf16x8*)
                &Ks[0][(kh * 32 + nt * 16 + col) * 64 + (((ks * 4 + quad) ^ (col & 7)) * 8)];
            sc[nt] = MFMA16(qf[ks], bk, sc[nt]);
        }

    int bb = 0, b1 = 1, b2 = 2;
#pragma unroll 1
    for (int t = 0; t < 32; ++t) {
        // ---- softmax(t): p = exp2(sc + pr*log2e); truncate-pack; l exact ----
#pragma unroll
        for (int r = 0; r < 4; ++r) {
            const int rowW = qg * 16 + quad * 4 + r;
            const int rsw  = rowW & 7;
#pragma unroll
            for (int nt = 0; nt < 2; ++nt) {
                const float e = __builtin_amdgcn_exp2f(
                    fmaf(pr[r][nt], LOG2E, sc[nt][r]));
                unsigned int u = __float_as_uint(e) & 0xffff0000u;
                u = mk[nt] ? u : 0u;
                lsum[r] += __uint_as_float(u);
                const int kk = kh * 32 + nt * 16 + col;
                Ps[rowW * 64 + (((kk >> 3) ^ rsw) * 8) + (kk & 7)] =
                    (unsigned short)(u >> 16);
            }
        }

        __syncthreads();                // B1: stage(t+1) ready, Ps(t) published

        if (t < 31) {                   // posr/mask prefetch for t+1
            const int kn = (t + 1) * 64;
#pragma unroll
            for (int r = 0; r < 4; ++r)
#pragma unroll
                for (int nt = 0; nt < 2; ++nt) pr[r][nt] = prq[r][kn + nt * 16 + col];
#pragma unroll
            for (int nt = 0; nt < 2; ++nt) mk[nt] = mrow[kn + nt * 16 + col];
        }
        if (t < 30) {                   // stage t+2 (buffer b2 free since B2(t-1))
            const int kn = (t + 2) * 64;
            if (isK) ASYNC16(Kh + (size_t)(kn + srow) * 64 + sg * 8,
                             &Ks[b2][(size_t)(w * 64) * 8]);
            else     ASYNC16(Vth + (size_t)srow * 2048 + kn + sg * 8,
                             &Vts[b2][(size_t)((w - 8) * 64) * 8]);
        }

        // ---- PV(t): O += P.V from buffer bb (full-k P, own d-half) ----
#pragma unroll
        for (int ks = 0; ks < 2; ++ks) {
            const bf16x8 ap = *(const bf16x8*)
                &Ps[(qg * 16 + col) * 64 + (((ks * 4 + quad) ^ (col & 7)) * 8)];
#pragma unroll
            for (int nt = 0; nt < 2; ++nt) {
                const bf16x8 vb = *(const bf16x8*)
                    &Vts[bb][(kh * 32 + nt * 16 + col) * 64 + (((ks * 4 + quad) ^ (col & 7)) * 8)];
                O[nt] = MFMA16(ap, vb, O[nt]);
            }
        }

        if (t < 31) {
            // ---- QK(t+1) from buffer b1 ----
#pragma unroll
            for (int nt = 0; nt < 2; ++nt) sc[nt] = (f32x4){0.f, 0.f, 0.f, 0.f};
#pragma unroll
            for (int ks = 0; ks < 2; ++ks)
#pragma unroll
                for (int nt = 0; nt < 2; ++nt) {
                    const bf16x8 bk = *(const bf16x8*)
                        &Ks[b1][(kh * 32 + nt * 16 + col) * 64 + (((ks * 4 + quad) ^ (col & 7)) * 8)];
                    sc[nt] = MFMA16(qf[ks], bk, sc[nt]);
                }
            // B2: all Ps reads (consumed by MFMAs) must complete before the
            // next iteration's Ps writes; do NOT drain vmcnt (stage t+2 and
            // posr t+1 stay in flight across the barrier).
            asm volatile("s_waitcnt lgkmcnt(0)" ::: "memory");
            __builtin_amdgcn_s_barrier();
            asm volatile("" ::: "memory");
        }
        const int tmp = bb; bb = b1; b1 = b2; b2 = tmp;
    }

    __syncthreads();                    // all PV(31) done; Ks reusable

    // ---- reduce l: 16 cols in-wave, then combine the two k-halves via LDS ----
#pragma unroll
    for (int r = 0; r < 4; ++r) {
#pragma unroll
        for (int o = 1; o < 16; o <<= 1) lsum[r] += __shfl_xor(lsum[r], o);
    }
    float* Lred = (float*)&Ks[0][0];
    if (col == 0) {
#pragma unroll
        for (int r = 0; r < 4; ++r)
            Lred[kh * 128 + qg * 16 + quad * 4 + r] = lsum[r];
    }
    __syncthreads();

    // ---- epilogue: ctx = O / l  (bf16), own d-half ----
#pragma unroll
    for (int r = 0; r < 4; ++r) {
        const int qloc = qg * 16 + quad * 4 + r;
        const float inv = 1.f / (Lred[qloc] + Lred[128 + qloc]);
        const size_t rowoff = ((size_t)b * 2048 + (q0 + qloc)) * 1024 + h * 64 + kh * 32;
#pragma unroll
        for (int nt = 0; nt < 2; ++nt)
            ctxb[rowoff + nt * 16 + col] = f2bf(O[nt][r] * inv);
    }
}

// ---------------------------------------------------------------------------
extern "C" void kernel_launch(void* const* d_in, const int* in_sizes, int n_in,
                              void* d_out, int out_size, void* d_ws, size_t ws_size,
                              hipStream_t stream) {
    const float* query = (const float*)d_in[0];
    const float* key   = (const float*)d_in[1];
    const float* value = (const float*)d_in[2];
    const int*   mask  = (const int*)  d_in[3];
    const float* posr  = (const float*)d_in[4];
    const float* Wq    = (const float*)d_in[5];
    const float* bq    = (const float*)d_in[6];
    const float* Wk    = (const float*)d_in[7];
    const float* bk    = (const float*)d_in[8];
    const float* Wv    = (const float*)d_in[9];
    const float* bv    = (const float*)d_in[10];
    const float* Wo    = (const float*)d_in[11];
    const float* bo    = (const float*)d_in[12];
    float* out = (float*)d_out;

    unsigned short* ws0   = (unsigned short*)d_ws;
    const size_t IN = 4194304, WT = 1048576;
    unsigned short* qbuf  = ws0 + 4 * IN;
    unsigned short* kbuf  = ws0 + 5 * IN;
    unsigned short* vtbuf = ws0 + 6 * IN;
    unsigned short* ctxb  = ws0 + 7 * IN;
    const unsigned short* wob = ws0 + 3 * IN + 3 * WT;

    pack_all<<<dim3(512, 1, 7), 256, 0, stream>>>(query, key, value, Wq, Wk, Wv, Wo, ws0);

    gemm_qkv<<<dim3(8, 32, 3), 512, 0, stream>>>(ws0, bq, bk, bv, qbuf, kbuf, vtbuf);

    attn_mfma<<<dim3(16, 16, 2), 1024, 0, stream>>>(qbuf, kbuf, vtbuf, posr, mask, ctxb);

    gemm_out<<<dim3(8, 32), 512, 0, stream>>>(ctxb, wob, bo, out);
}

// Round 2
// 273.139 us; speedup vs baseline: 1.7897x; 1.7897x over previous
//
#include <hip/hip_runtime.h>
#include <math.h>

#define B_ 2
#define S_ 2048
#define D_ 1024
#define H_ 16
#define DK_ 64

typedef __attribute__((ext_vector_type(8))) short bf16x8;
typedef __attribute__((ext_vector_type(4))) float f32x4;

#define MFMA16(a, b, c) __builtin_amdgcn_mfma_f32_16x16x32_bf16((a), (b), (c), 0, 0, 0)

#define ASYNC16(g, l)                                                          \
    __builtin_amdgcn_global_load_lds(                                          \
        (const __attribute__((address_space(1))) void*)(g),                    \
        (__attribute__((address_space(3))) void*)(l), 16, 0, 0)

#define LOG2E 1.4426950408889634f

__device__ __forceinline__ unsigned short f2bf(float x) {
    unsigned int u = __float_as_uint(x);
    unsigned int r = (u + 0x7fffu + ((u >> 16) & 1u)) >> 16;
    return (unsigned short)r;
}

// ---------------------------------------------------------------------------
// pack: fp32 -> bf16 (plain), z selects tensor.
// ---------------------------------------------------------------------------
__global__ __launch_bounds__(256)
void pack_all(const float* __restrict__ q, const float* __restrict__ k,
              const float* __restrict__ v, const float* __restrict__ wq,
              const float* __restrict__ wk, const float* __restrict__ wv,
              const float* __restrict__ wo, unsigned short* __restrict__ ws0)
{
    const int z = blockIdx.z;
    const size_t IN = 4194304, WT = 1048576;
    const float* in;
    unsigned short* dst;
    int n;
    switch (z) {
        case 0: in = q;  dst = ws0;            n = (int)IN; break;
        case 1: in = k;  dst = ws0 + IN;       n = (int)IN; break;
        case 2: in = v;  dst = ws0 + 2*IN;     n = (int)IN; break;
        case 3: in = wq; dst = ws0 + 3*IN;          n = (int)WT; break;
        case 4: in = wk; dst = ws0 + 3*IN + WT;     n = (int)WT; break;
        case 5: in = wv; dst = ws0 + 3*IN + 2*WT;   n = (int)WT; break;
        default:in = wo; dst = ws0 + 3*IN + 3*WT;   n = (int)WT; break;
    }
    const int n4 = n >> 2;
    const int stride = gridDim.x * blockDim.x;
    for (int i = blockIdx.x * blockDim.x + threadIdx.x; i < n4; i += stride) {
        float4 x = ((const float4*)in)[i];
        ushort4 hv;
        hv.x = f2bf(x.x); hv.y = f2bf(x.y); hv.z = f2bf(x.z); hv.w = f2bf(x.w);
        ((ushort4*)dst)[i] = hv;
    }
}

// ---------------------------------------------------------------------------
// bf16 GEMM core, 512 thr / 8 waves: acc += A(M,K).B(N,K)^T.  128x128 tile,
// BK=64, wave tile 64x32 (2x4 wave grid).  128B LDS rows + XOR-8 swizzle.
// ---------------------------------------------------------------------------
__device__ __forceinline__ void gemm_core512(
    const unsigned short* __restrict__ A, const unsigned short* __restrict__ B,
    unsigned short* As, unsigned short* Bs, int m0, int n0, f32x4 (&acc)[4][2])
{
    const int tid  = threadIdx.x;
    const int w    = tid >> 6;
    const int lane = tid & 63;
    const int rA   = lane & 15;
    const int quad = lane >> 4;
    const int wm   = (w & 1) * 64;
    const int wn   = (w >> 1) * 32;

#pragma unroll 1
    for (int k0 = 0; k0 < 1024; k0 += 64) {
        __syncthreads();
#pragma unroll
        for (int i = 0; i < 2; ++i) {
            const int c   = i * 512 + tid;
            const int row = c >> 3;
            const int g   = (c & 7) ^ (row & 7);
            ASYNC16(A + (size_t)(m0 + row) * 1024 + k0 + g * 8,
                    As + (size_t)(i * 512 + w * 64) * 8);
            ASYNC16(B + (size_t)(n0 + row) * 1024 + k0 + g * 8,
                    Bs + (size_t)(i * 512 + w * 64) * 8);
        }
        __syncthreads();
#pragma unroll
        for (int ks = 0; ks < 2; ++ks) {
            bf16x8 a[4], bb2[2];
#pragma unroll
            for (int mt = 0; mt < 4; ++mt) {
                const int row = wm + mt * 16 + rA;
                a[mt] = *(const bf16x8*)&As[row * 64 + (((ks * 4 + quad) ^ (row & 7)) * 8)];
            }
#pragma unroll
            for (int nt = 0; nt < 2; ++nt) {
                const int row = wn + nt * 16 + rA;
                bb2[nt] = *(const bf16x8*)&Bs[row * 64 + (((ks * 4 + quad) ^ (row & 7)) * 8)];
            }
#pragma unroll
            for (int mt = 0; mt < 4; ++mt)
#pragma unroll
                for (int nt = 0; nt < 2; ++nt)
                    acc[mt][nt] = MFMA16(a[mt], bb2[nt], acc[mt][nt]);
        }
    }
}

// QKV projections.  q,k -> (b,h,s,dk); v -> (b,h,dk,s).
// q pre-scaled by 0.125*log2(e) so attention uses exp2 directly.
__global__ __launch_bounds__(512, 4)
void gemm_qkv(const unsigned short* __restrict__ ws0,
              const float* __restrict__ bq, const float* __restrict__ bk,
              const float* __restrict__ bv,
              unsigned short* __restrict__ qbuf, unsigned short* __restrict__ kbuf,
              unsigned short* __restrict__ vtbuf)
{
    __shared__ unsigned short As[128 * 64];
    __shared__ unsigned short Bs[128 * 64];
    const size_t IN = 4194304, WT = 1048576;
    const int z = blockIdx.z;
    const unsigned short* Ap = ws0 + (size_t)z * IN;
    const unsigned short* Bp = ws0 + 3 * IN + (size_t)z * WT;
    const float* bias = (z == 0) ? bq : (z == 1) ? bk : bv;
    unsigned short* dst = (z == 0) ? qbuf : (z == 1) ? kbuf : vtbuf;

    const int m0 = blockIdx.y * 128;
    const int n0 = blockIdx.x * 128;
    f32x4 acc[4][2] = {};
    gemm_core512(Ap, Bp, As, Bs, m0, n0, acc);

    const int tid = threadIdx.x, w = tid >> 6, lane = tid & 63;
    const int quad = lane >> 4, col = lane & 15;
    const int wm = (w & 1) * 64, wn = (w >> 1) * 32;
    const float qscale = (z == 0) ? (0.125f * LOG2E) : 1.0f;
#pragma unroll
    for (int mt = 0; mt < 4; ++mt)
#pragma unroll
        for (int nt = 0; nt < 2; ++nt) {
            f32x4 v = acc[mt][nt];
#pragma unroll
            for (int r = 0; r < 4; ++r) {
                const int m = m0 + wm + mt * 16 + quad * 4 + r;
                const int n = n0 + wn + nt * 16 + col;
                const float val = (v[r] + bias[n]) * qscale;
                const int bb = m >> 11, ss = m & 2047;
                const int hh = n >> 6, dd = n & 63;
                if (z == 2)
                    dst[((size_t)(bb * 16 + hh) * 64 + dd) * 2048 + ss] = f2bf(val);
                else
                    dst[((size_t)(bb * 16 + hh) * 2048 + ss) * 64 + dd] = f2bf(val);
            }
        }
}

// Output projection: out = ctx(bf16) . Wo^T + bo, fp32 out.
__global__ __launch_bounds__(512, 4)
void gemm_out(const unsigned short* __restrict__ Actx,
              const unsigned short* __restrict__ Bwo,
              const float* __restrict__ bias, float* __restrict__ out)
{
    __shared__ unsigned short As[128 * 64];
    __shared__ unsigned short Bs[128 * 64];
    const int m0 = blockIdx.y * 128;
    const int n0 = blockIdx.x * 128;
    f32x4 acc[4][2] = {};
    gemm_core512(Actx, Bwo, As, Bs, m0, n0, acc);

    const int tid = threadIdx.x, w = tid >> 6, lane = tid & 63;
    const int quad = lane >> 4, col = lane & 15;
    const int wm = (w & 1) * 64, wn = (w >> 1) * 32;
#pragma unroll
    for (int mt = 0; mt < 4; ++mt)
#pragma unroll
        for (int nt = 0; nt < 2; ++nt) {
            f32x4 v = acc[mt][nt];
#pragma unroll
            for (int r = 0; r < 4; ++r) {
                const int m = m0 + wm + mt * 16 + quad * 4 + r;
                const int n = n0 + wn + nt * 16 + col;
                out[(size_t)m * 1024 + n] = v[r] + bias[n];
            }
        }
}

// ---------------------------------------------------------------------------
// Flash attention, 256 thr = 4 waves, each wave owns 32 q-rows (mt=2).
// Rationale: round-0 was LDS-read-BW bound (each of 8 waves re-read the whole
// K/V tile: 144 KB ds_read per block-tile).  With 32 rows/wave each K/V
// fragment feeds 2 MFMAs -> 80 KB per block-tile (-44%).
// Pipeline: K/V triple-buffered, staged 2 tiles ahead; posr 1 tile ahead with
// PV+QK as latency cover; per-tile barrier is raw s_barrier + lgkmcnt(0) only
// (no vmcnt drain).  Safety: posr loads are pinned (sched_barrier) after the
// ASYNC16s, so the compiler's wait on pr at softmax(t) implies (in-order
// vmcnt retirement) all earlier stages completed; buffer WAR is separated by
// a barrier with lgkm drained.  Ps rows are wave-private (in-order DS per
// wave), so one barrier per tile suffices.
// ---------------------------------------------------------------------------
__global__ __launch_bounds__(256, 2)
void attn_mfma(const unsigned short* __restrict__ qbuf,
               const unsigned short* __restrict__ kbuf,
               const unsigned short* __restrict__ vtbuf,
               const float* __restrict__ posr, const int* __restrict__ mask,
               unsigned short* __restrict__ ctxb)
{
    __shared__ unsigned short Ks[3][64 * 64];
    __shared__ unsigned short Vts[3][64 * 64];
    __shared__ unsigned short Ps[128 * 64];

    const int tid  = threadIdx.x;
    const int w    = tid >> 6;          // wave 0..3
    const int lane = tid & 63;
    const int quad = lane >> 4;
    const int col  = lane & 15;
    const int q0   = blockIdx.x * 128;
    const int h    = blockIdx.y;
    const int b    = blockIdx.z;
    const int wq   = w * 32;            // 32 q-rows per wave

    const size_t headoff = (size_t)(b * 16 + h) * 2048 * 64;
    const unsigned short* Qh  = qbuf + headoff + (size_t)q0 * 64;
    const unsigned short* Kh  = kbuf + headoff;
    const unsigned short* Vth = vtbuf + headoff;

    // staging geometry: 2 chunks per thread per tensor per tile
    const int c0 = tid;
    const int c1 = 256 + tid;
    const int r0 = c0 >> 3, g0 = (c0 & 7) ^ (r0 & 7);
    const int r1 = c1 >> 3, g1 = (c1 & 7) ^ (r1 & 7);

#define STAGE(bufidx, kt) do {                                                  \
        ASYNC16(Kh + (size_t)((kt) * 64 + r0) * 64 + g0 * 8,                    \
                &Ks[bufidx][(size_t)(w * 64) * 8]);                             \
        ASYNC16(Kh + (size_t)((kt) * 64 + r1) * 64 + g1 * 8,                    \
                &Ks[bufidx][(size_t)(256 + w * 64) * 8]);                       \
        ASYNC16(Vth + (size_t)r0 * 2048 + (kt) * 64 + g0 * 8,                   \
                &Vts[bufidx][(size_t)(w * 64) * 8]);                            \
        ASYNC16(Vth + (size_t)r1 * 2048 + (kt) * 64 + g1 * 8,                   \
                &Vts[bufidx][(size_t)(256 + w * 64) * 8]);                      \
    } while (0)

    // Q fragments (A-layout: m=col, k=ks*32+quad*8+j), 2 m-tiles x 2 ks
    bf16x8 qf[2][2];
#pragma unroll
    for (int mt = 0; mt < 2; ++mt)
#pragma unroll
        for (int ks = 0; ks < 2; ++ks)
            qf[mt][ks] = *(const bf16x8*)
                &Qh[(size_t)(wq + mt * 16 + col) * 64 + ks * 32 + quad * 8];

    // posr row pointers (8 rows per lane: mt x r)
    const float* prq[2][4];
#pragma unroll
    for (int mt = 0; mt < 2; ++mt)
#pragma unroll
        for (int r = 0; r < 4; ++r)
            prq[mt][r] = posr +
                ((size_t)b * 2048 + (q0 + wq + mt * 16 + quad * 4 + r)) * 2048;
    const int* mrow = mask + (size_t)b * 2048;

    // stage tiles 0,1
    STAGE(0, 0);
    STAGE(1, 1);

    // posr/mask for tile 0
    float pr[2][4][4];
    int   mk[4];
#pragma unroll
    for (int mt = 0; mt < 2; ++mt)
#pragma unroll
        for (int r = 0; r < 4; ++r)
#pragma unroll
            for (int nt = 0; nt < 4; ++nt)
                pr[mt][r][nt] = prq[mt][r][nt * 16 + col];
#pragma unroll
    for (int nt = 0; nt < 4; ++nt) mk[nt] = mrow[nt * 16 + col];

    f32x4 sc[2][4];
    f32x4 O[2][4] = {};
    float lsum[2][4] = {{0.f, 0.f, 0.f, 0.f}, {0.f, 0.f, 0.f, 0.f}};

    __syncthreads();                    // tiles 0,1 staged (full drain, once)

    // QK(0) from buffer 0
#pragma unroll
    for (int mt = 0; mt < 2; ++mt)
#pragma unroll
        for (int nt = 0; nt < 4; ++nt) sc[mt][nt] = (f32x4){0.f, 0.f, 0.f, 0.f};
#pragma unroll
    for (int nt = 0; nt < 4; ++nt)
#pragma unroll
        for (int ks = 0; ks < 2; ++ks) {
            const bf16x8 bk = *(const bf16x8*)
                &Ks[0][(nt * 16 + col) * 64 + (((ks * 4 + quad) ^ (col & 7)) * 8)];
#pragma unroll
            for (int mt = 0; mt < 2; ++mt)
                sc[mt][nt] = MFMA16(qf[mt][ks], bk, sc[mt][nt]);
        }

    int bb = 0, b1 = 1, b2 = 2;
#pragma unroll 1
    for (int t = 0; t < 32; ++t) {
        // ---- softmax(t): p = exp2(sc + pr*log2e); truncate-pack; l exact ----
#pragma unroll
        for (int mt = 0; mt < 2; ++mt)
#pragma unroll
            for (int r = 0; r < 4; ++r) {
                const int rowW = wq + mt * 16 + quad * 4 + r;
                const int rsw  = rowW & 7;
#pragma unroll
                for (int nt = 0; nt < 4; ++nt) {
                    const float e = __builtin_amdgcn_exp2f(
                        fmaf(pr[mt][r][nt], LOG2E, sc[mt][nt][r]));
                    unsigned int u = __float_as_uint(e) & 0xffff0000u;
                    u = mk[nt] ? u : 0u;
                    lsum[mt][r] += __uint_as_float(u);
                    const int kk = nt * 16 + col;
                    Ps[rowW * 64 + (((kk >> 3) ^ rsw) * 8) + (kk & 7)] =
                        (unsigned short)(u >> 16);
                }
            }

        // barrier: publish Ps(t); stage(t+1) already covered by softmax's
        // wait on pr(t) (posr loads pinned after stages).  No vmcnt drain.
        __builtin_amdgcn_sched_barrier(0);
        asm volatile("s_waitcnt lgkmcnt(0)" ::: "memory");
        __builtin_amdgcn_s_barrier();
        __builtin_amdgcn_sched_barrier(0);

        // stage t+2 into b2 (its previous readers retired before last barrier)
        if (t < 30) STAGE(b2, t + 2);
        __builtin_amdgcn_sched_barrier(0);   // pin: stages BEFORE posr loads

        // posr/mask prefetch for t+1 (cover = PV + QK below)
        if (t < 31) {
            const int kn = (t + 1) * 64;
#pragma unroll
            for (int mt = 0; mt < 2; ++mt)
#pragma unroll
                for (int r = 0; r < 4; ++r)
#pragma unroll
                    for (int nt = 0; nt < 4; ++nt)
                        pr[mt][r][nt] = prq[mt][r][kn + nt * 16 + col];
#pragma unroll
            for (int nt = 0; nt < 4; ++nt) mk[nt] = mrow[kn + nt * 16 + col];
        }

        // ---- PV(t): O += P.V from buffer bb ----
#pragma unroll
        for (int ks = 0; ks < 2; ++ks) {
            bf16x8 pa[2];
#pragma unroll
            for (int mt = 0; mt < 2; ++mt)
                pa[mt] = *(const bf16x8*)
                    &Ps[(wq + mt * 16 + col) * 64 + (((ks * 4 + quad) ^ (col & 7)) * 8)];
#pragma unroll
            for (int nt = 0; nt < 4; ++nt) {
                const bf16x8 vb = *(const bf16x8*)
                    &Vts[bb][(nt * 16 + col) * 64 + (((ks * 4 + quad) ^ (col & 7)) * 8)];
#pragma unroll
                for (int mt = 0; mt < 2; ++mt)
                    O[mt][nt] = MFMA16(pa[mt], vb, O[mt][nt]);
            }
        }

        // ---- QK(t+1) from buffer b1 ----
        if (t < 31) {
#pragma unroll
            for (int mt = 0; mt < 2; ++mt)
#pragma unroll
                for (int nt = 0; nt < 4; ++nt)
                    sc[mt][nt] = (f32x4){0.f, 0.f, 0.f, 0.f};
#pragma unroll
            for (int nt = 0; nt < 4; ++nt)
#pragma unroll
                for (int ks = 0; ks < 2; ++ks) {
                    const bf16x8 bk = *(const bf16x8*)
                        &Ks[b1][(nt * 16 + col) * 64 + (((ks * 4 + quad) ^ (col & 7)) * 8)];
#pragma unroll
                    for (int mt = 0; mt < 2; ++mt)
                        sc[mt][nt] = MFMA16(qf[mt][ks], bk, sc[mt][nt]);
                }
        }
        const int tmp = bb; bb = b1; b1 = b2; b2 = tmp;
    }

    // ---- reduce l across the 16 cols (rows are wave-private) ----
#pragma unroll
    for (int mt = 0; mt < 2; ++mt)
#pragma unroll
        for (int r = 0; r < 4; ++r) {
#pragma unroll
            for (int o = 1; o < 16; o <<= 1)
                lsum[mt][r] += __shfl_xor(lsum[mt][r], o);
        }

    // ---- epilogue: ctx = O / l (bf16) ----
#pragma unroll
    for (int mt = 0; mt < 2; ++mt)
#pragma unroll
        for (int r = 0; r < 4; ++r) {
            const float inv = 1.f / lsum[mt][r];
            const int rowW = wq + mt * 16 + quad * 4 + r;
            const size_t rowoff =
                ((size_t)b * 2048 + (q0 + rowW)) * 1024 + h * 64;
#pragma unroll
            for (int nt = 0; nt < 4; ++nt)
                ctxb[rowoff + nt * 16 + col] = f2bf(O[mt][nt][r] * inv);
        }
#undef STAGE
}

// ---------------------------------------------------------------------------
extern "C" void kernel_launch(void* const* d_in, const int* in_sizes, int n_in,
                              void* d_out, int out_size, void* d_ws, size_t ws_size,
                              hipStream_t stream) {
    const float* query = (const float*)d_in[0];
    const float* key   = (const float*)d_in[1];
    const float* value = (const float*)d_in[2];
    const int*   mask  = (const int*)  d_in[3];
    const float* posr  = (const float*)d_in[4];
    const float* Wq    = (const float*)d_in[5];
    const float* bq    = (const float*)d_in[6];
    const float* Wk    = (const float*)d_in[7];
    const float* bk    = (const float*)d_in[8];
    const float* Wv    = (const float*)d_in[9];
    const float* bv    = (const float*)d_in[10];
    const float* Wo    = (const float*)d_in[11];
    const float* bo    = (const float*)d_in[12];
    float* out = (float*)d_out;

    unsigned short* ws0   = (unsigned short*)d_ws;
    const size_t IN = 4194304, WT = 1048576;
    unsigned short* qbuf  = ws0 + 4 * IN;
    unsigned short* kbuf  = ws0 + 5 * IN;
    unsigned short* vtbuf = ws0 + 6 * IN;
    unsigned short* ctxb  = ws0 + 7 * IN;
    const unsigned short* wob = ws0 + 3 * IN + 3 * WT;

    pack_all<<<dim3(512, 1, 7), 256, 0, stream>>>(query, key, value, Wq, Wk, Wv, Wo, ws0);

    gemm_qkv<<<dim3(8, 32, 3), 512, 0, stream>>>(ws0, bq, bk, bv, qbuf, kbuf, vtbuf);

    attn_mfma<<<dim3(16, 16, 2), 256, 0, stream>>>(qbuf, kbuf, vtbuf, posr, mask, ctxb);

    gemm_out<<<dim3(8, 32), 512, 0, stream>>>(ctxb, wob, bo, out);
}